// Round 16
// baseline (365.573 us; speedup 1.0000x reference)
//
#include <hip/hip_runtime.h>
#include <hip/hip_bf16.h>
#include <stdint.h>

#define Bdim 4
#define Sdim 2048
#define Edim 2048
#define Hdim 16
#define Ddim 128

typedef unsigned short u16;
typedef unsigned int u32;
typedef __attribute__((ext_vector_type(8))) short bf16x8;
typedef __attribute__((ext_vector_type(4))) float f32x4;
typedef __attribute__((ext_vector_type(16))) float f32x16;
typedef __attribute__((ext_vector_type(4))) unsigned short u16x4;
typedef __attribute__((ext_vector_type(2))) unsigned int u32x2;

__device__ inline u16 f2bf(float f) {
  union { float f; uint32_t u; } v; v.f = f;
  uint32_t u = v.u;
  return (u16)((u + 0x7FFFu + ((u >> 16) & 1u)) >> 16);
}

__device__ inline u32 pkbf(float lo, float hi) {
  float2 t; t.x = lo; t.y = hi;
  union { __hip_bfloat162 h2; u32 u; } cv;
  cv.h2 = __float22bfloat162_rn(t);
  return cv.u;
}

__device__ inline f32x4 mfma16(bf16x8 a, bf16x8 b, f32x4 c) {
  return __builtin_amdgcn_mfma_f32_16x16x32_bf16(a, b, c, 0, 0, 0);
}
__device__ inline f32x16 mfma32(bf16x8 a, bf16x8 b, f32x16 c) {
  return __builtin_amdgcn_mfma_f32_32x32x16_bf16(a, b, c, 0, 0, 0);
}

// async global->LDS, 16B per lane; lds dest = wave-uniform base + lane*16
__device__ inline void load_lds16(const void* g, const void* l) {
  __builtin_amdgcn_global_load_lds(
      (__attribute__((address_space(1))) void*)(uintptr_t)g,
      (__attribute__((address_space(3))) void*)(uint32_t)(uintptr_t)l,
      16, 0, 0);
}

__global__ void cvt_kernel(const float* __restrict__ src, u16* __restrict__ dst,
                           int n4, float scale) {
  int i = blockIdx.x * blockDim.x + threadIdx.x;
  if (i < n4) {
    float4 f = ((const float4*)src)[i];
    u16x4 o = { f2bf(f.x * scale), f2bf(f.y * scale),
                f2bf(f.z * scale), f2bf(f.w * scale) };
    ((u16x4*)dst)[i] = o;
  }
}

// fused Wq/Wk/Wv cvt; dst = contiguous wqb|wkb|wvb region; Wq pre-scaled
__global__ void cvt_w_kernel(const float* __restrict__ Wq,
                             const float* __restrict__ Wk,
                             const float* __restrict__ Wv,
                             u16* __restrict__ dst, float qscale) {
  int i = blockIdx.x * blockDim.x + threadIdx.x;  // over 3 * (E*E/4)
  int seg = i >> 20;                              // E*E/4 = 1048576
  int off = i & 1048575;
  const float* src = seg == 0 ? Wq : (seg == 1 ? Wk : Wv);
  float sc = seg == 0 ? qscale : 1.0f;
  float4 f = ((const float4*)src)[off];
  u16x4 o = { f2bf(f.x * sc), f2bf(f.y * sc), f2bf(f.z * sc), f2bf(f.w * sc) };
  ((u16x4*)dst)[i] = o;
}

// C[m][n] = sum_k A[m][k] * Bw[n][k]   (A:[M][K], Bw:[N][K], bf16 in/out)
// 4-phase/BK=64 m201 schedule, 3-barrier variant: phases 2+3 merged (phase 3
// read nothing from LDS, so its entry barrier published nothing -- removed).
// Barriers publish: ph0-end Bh1(t) [vmcnt(4)], ph1-end Ah1(t) [vmcnt(4)],
// ph2-end Ah0/Bh0(t+1) [vmcnt(4)]. Steady-state invariant: exactly
// {Bh1(t+1),Ah1(t+1)} (4 loads) outstanding at tile entry; never vmcnt(0)
// mid-loop. Fragment maps: row(m)=(m&3)*32+wm*16+(m>>2)*128, col(n)=
// (n&1)*64+wn*16+(n>>1)*128. Swizzle: read chunk=(kk*4+l4)^(l15&7), stage
// src chunk=(lane&7)^(lane>>3). TRANSV: store into Vt[(b*H+h)][d][s].
template <bool TRANSV>
__global__ __launch_bounds__(512, 2)
void gemm_nt(const u16* __restrict__ A, const u16* __restrict__ Bw,
             u16* __restrict__ C, int M, int N, int K) {
  __shared__ char lds[131072];  // [2 buf][Ah0|Ah1|Bh0|Bh1]

  const int tid = threadIdx.x;
  const int lane = tid & 63;
  const int w = tid >> 6;            // 0..7
  const int wm = w >> 2, wn = w & 3; // 2 x 4 wave grid
  const int bm = blockIdx.x, bn = blockIdx.y;
  const int NT = K >> 6;             // K-tiles of 64

  const int l15 = lane & 15;
  const int l4 = lane >> 4;          // k-subchunk 0..3
  const int h7 = l15 & 7;

  // stage lane constants: per half-tile 2 issues; issue i covers rows
  // w*8+srow + i*64 (8 rows x 128B per wave per issue)
  const int srow = lane >> 3;               // 0..7
  const int schunk = (lane & 7) ^ srow;     // pre-swizzled source chunk

  // fragment byte offsets within a half (lrow*128 + chunk*16)
  const int ck0 = (l4 ^ h7) << 4;           // kk=0
  const int ck1 = ((4 + l4) ^ h7) << 4;     // kk=1
  const int arow0 = (wm * 16 + l15) * 128;  // A q-base; q adds 4096
  const int brow0 = (wn * 16 + l15) * 128;  // B n-base; (n&1) adds 8192

  const u16* Agp = A + (size_t)(bm * 256) * K;
  const u16* Bgp = Bw + (size_t)(bn * 256) * K;

  f32x4 acc[8][4];
#pragma unroll
  for (int m = 0; m < 8; ++m)
#pragma unroll
    for (int n = 0; n < 4; ++n)
      acc[m][n] = (f32x4){0.f, 0.f, 0.f, 0.f};

#define STG_A(hh, tt)                                                          \
  {                                                                            \
    char* d_ = lds + ((tt) & 1) * 65536 + (hh) * 16384;                        \
    _Pragma("unroll")                                                          \
    for (int i_ = 0; i_ < 2; ++i_)                                             \
      load_lds16(Agp + (size_t)((hh) * 128 + w * 8 + srow + i_ * 64) * K +     \
                     (tt) * 64 + schunk * 8,                                   \
                 d_ + (w * 8 + i_ * 64) * 128);                                \
  }
#define STG_B(hh, tt)                                                          \
  {                                                                            \
    char* d_ = lds + ((tt) & 1) * 65536 + 32768 + (hh) * 16384;                \
    _Pragma("unroll")                                                          \
    for (int i_ = 0; i_ < 2; ++i_)                                             \
      load_lds16(Bgp + (size_t)((hh) * 128 + w * 8 + srow + i_ * 64) * K +     \
                     (tt) * 64 + schunk * 8,                                   \
                 d_ + (w * 8 + i_ * 64) * 128);                                \
  }

  // prologue: all 4 halves of tile 0, in steady-state order
  STG_A(0, 0); STG_B(0, 0); STG_B(1, 0); STG_A(1, 0);
  asm volatile("s_waitcnt vmcnt(0)" ::: "memory");
  __builtin_amdgcn_s_barrier();

  for (int t = 0; t < NT; ++t) {
    const char* bc = lds + (t & 1) * 65536;
    const bool pf = (t + 1 < NT);

    // ---- phase 0: stage Ah0(t+1) | read a0,b0 | MFMA m0-3 x n0-1 ----
    if (pf) STG_A(0, t + 1);
    bf16x8 a0[4][2], b0[2][2];
#pragma unroll
    for (int q = 0; q < 4; ++q) {
      a0[q][0] = *(const bf16x8*)(bc + arow0 + q * 4096 + ck0);
      a0[q][1] = *(const bf16x8*)(bc + arow0 + q * 4096 + ck1);
    }
#pragma unroll
    for (int n = 0; n < 2; ++n) {
      b0[n][0] = *(const bf16x8*)(bc + 32768 + brow0 + n * 8192 + ck0);
      b0[n][1] = *(const bf16x8*)(bc + 32768 + brow0 + n * 8192 + ck1);
    }
    __builtin_amdgcn_s_setprio(1);
#pragma unroll
    for (int q = 0; q < 4; ++q)
#pragma unroll
      for (int n = 0; n < 2; ++n) {
        acc[q][n] = mfma16(a0[q][0], b0[n][0], acc[q][n]);
        acc[q][n] = mfma16(a0[q][1], b0[n][1], acc[q][n]);
      }
    __builtin_amdgcn_s_setprio(0);
    if (pf) {
      asm volatile("s_waitcnt vmcnt(4)" ::: "memory");  // retires Bh1(t)
    } else {
      asm volatile("s_waitcnt vmcnt(0)" ::: "memory");
    }
    __builtin_amdgcn_s_barrier();

    // ---- phase 1: stage Bh0(t+1) | read b1 | MFMA m0-3 x n2-3 ----
    if (pf) STG_B(0, t + 1);
    bf16x8 b1[2][2];
#pragma unroll
    for (int n = 0; n < 2; ++n) {
      b1[n][0] = *(const bf16x8*)(bc + 49152 + brow0 + n * 8192 + ck0);
      b1[n][1] = *(const bf16x8*)(bc + 49152 + brow0 + n * 8192 + ck1);
    }
    __builtin_amdgcn_s_setprio(1);
#pragma unroll
    for (int q = 0; q < 4; ++q)
#pragma unroll
      for (int n = 0; n < 2; ++n) {
        acc[q][n + 2] = mfma16(a0[q][0], b1[n][0], acc[q][n + 2]);
        acc[q][n + 2] = mfma16(a0[q][1], b1[n][1], acc[q][n + 2]);
      }
    __builtin_amdgcn_s_setprio(0);
    if (pf) {
      asm volatile("s_waitcnt vmcnt(4)" ::: "memory");  // retires Ah1(t)
    } else {
      asm volatile("s_waitcnt vmcnt(0)" ::: "memory");
    }
    __builtin_amdgcn_s_barrier();

    // ---- phase 2 (merged 2+3): stage Bh1(t+1) | read a1 | MFMA m4-7 x n2-3
    //      | stage Ah1(t+1) | MFMA m4-7 x n0-1 ----
    if (pf) STG_B(1, t + 1);
    bf16x8 a1[4][2];
#pragma unroll
    for (int q = 0; q < 4; ++q) {
      a1[q][0] = *(const bf16x8*)(bc + 16384 + arow0 + q * 4096 + ck0);
      a1[q][1] = *(const bf16x8*)(bc + 16384 + arow0 + q * 4096 + ck1);
    }
    __builtin_amdgcn_s_setprio(1);
#pragma unroll
    for (int q = 0; q < 4; ++q)
#pragma unroll
      for (int n = 0; n < 2; ++n) {
        acc[q + 4][n + 2] = mfma16(a1[q][0], b1[n][0], acc[q + 4][n + 2]);
        acc[q + 4][n + 2] = mfma16(a1[q][1], b1[n][1], acc[q + 4][n + 2]);
      }
    __builtin_amdgcn_s_setprio(0);
    if (pf) STG_A(1, t + 1);
    __builtin_amdgcn_s_setprio(1);
#pragma unroll
    for (int q = 0; q < 4; ++q)
#pragma unroll
      for (int n = 0; n < 2; ++n) {
        acc[q + 4][n] = mfma16(a1[q][0], b0[n][0], acc[q + 4][n]);
        acc[q + 4][n] = mfma16(a1[q][1], b0[n][1], acc[q + 4][n]);
      }
    __builtin_amdgcn_s_setprio(0);
    if (pf) {
      asm volatile("s_waitcnt vmcnt(4)" ::: "memory");  // retires Ah0/Bh0(t+1)
    } else {
      asm volatile("s_waitcnt vmcnt(0)" ::: "memory");
    }
    __builtin_amdgcn_s_barrier();
  }
#undef STG_A
#undef STG_B

  // epilogue: row(m) = (m&3)*32 + wm*16 + (m>>2)*128; col(n) = (n&1)*64 +
  // wn*16 + (n>>1)*128; within-frag: row += l4*4 + j, col += l15.
#pragma unroll
  for (int m = 0; m < 8; ++m)
#pragma unroll
    for (int n = 0; n < 4; ++n) {
      int r = bm * 256 + (m & 3) * 32 + wm * 16 + (m >> 2) * 128 + (l4 << 2);
      int c = bn * 256 + (n & 1) * 64 + wn * 16 + (n >> 1) * 128 + l15;
      if (!TRANSV) {
#pragma unroll
        for (int j = 0; j < 4; ++j)
          C[(size_t)(r + j) * N + c] = f2bf(acc[m][n][j]);
      } else {
        int h = c >> 7, d = c & 127;
        int b = r >> 11, s = r & 2047;
        u16x4 pk = { f2bf(acc[m][n][0]), f2bf(acc[m][n][1]),
                     f2bf(acc[m][n][2]), f2bf(acc[m][n][3]) };
        *(u16x4*)(C + ((size_t)((b * Hdim + h) * Ddim + d)) * Sdim + s) = pk;
      }
    }
}

// Causal flash attention, swapped-operand 32x32 MFMA (round-5 verbatim —
// measured best 154us; frozen). Block = 4 waves sharing one head and a
// 128-row q-block; each wave owns 32 q rows. KV tile = 64, double-buffered in
// LDS (K swizzled ^row&15, V ^row&7), staged via global_load_lds with
// pre-swizzled global source; 2-phase pipeline. Q PRE-SCALED by
// log2e/sqrt(D); row sums via ones-MFMA into lacc; P redistribution via
// v_permlane32_swap; defer-max rescale (THR=8).
__global__ __launch_bounds__(256)
void attn_kernel(const u16* __restrict__ Q, const u16* __restrict__ K,
                 const u16* __restrict__ Vt, float* __restrict__ O) {
  __shared__ u16 Ks[2][64 * 128];
  __shared__ u16 Vs[2][128 * 64];

  const int tid = threadIdx.x;
  const int lane = tid & 63;
  const int w = tid >> 6;
  const int l31 = lane & 31;
  const int hi = lane >> 5;

  const int bid = blockIdx.x;
  const int bh = bid & 63;              // head index b*16+h
  const int qg = 15 - (bid >> 6);       // longest q-groups dispatch first
  const int q0 = qg * 128;
  const int qw0 = q0 + w * 32;          // this wave's 32 q rows
  const int b = bh >> 4, h = bh & 15;

  const u16* Qb = Q + (size_t)b * Sdim * Edim + h * Ddim;
  const u16* Kb = K + (size_t)b * Sdim * Edim + h * Ddim;
  const u16* Vb = Vt + (size_t)bh * Ddim * Sdim;

  // Q fragments (B-operand): lane: q row = qw0+l31, k = c*16 + hi*8 + e
  bf16x8 qf[8];
  {
    const u16* qrow = Qb + (size_t)(qw0 + l31) * Edim + hi * 8;
#pragma unroll
    for (int c = 0; c < 8; ++c) qf[c] = *(const bf16x8*)(qrow + c * 16);
  }

  f32x16 oacc[4];
#pragma unroll
  for (int d = 0; d < 4; ++d)
#pragma unroll
    for (int i = 0; i < 16; ++i) oacc[d][i] = 0.f;
  f32x16 lacc;
#pragma unroll
  for (int i = 0; i < 16; ++i) lacc[i] = 0.f;

  const short oneb = (short)0x3F80;
  const bf16x8 ones = {oneb, oneb, oneb, oneb, oneb, oneb, oneb, oneb};

  float m2 = -1e30f;
  const int qrel = qw0 + l31;

  const int nt = 2 * qg + 2;                 // block's causal tile count
  const int ntw = (qw0 + 31) / 64 + 1;       // this wave's tile count

  // staging lane constants
  const int krow_off = (lane >> 4);          // K: 4 rows per 1KB issue
  const int kchunk = lane & 15;
  const int vrow_off = (lane >> 3);          // V: 8 rows per 1KB issue
  const int vchunk = lane & 7;

#define STAGE(bufi, tt)                                                        \
  {                                                                            \
    const int kv0s = (tt) * 64;                                                \
    _Pragma("unroll")                                                          \
    for (int i = 0; i < 4; ++i) {                                              \
      const int rbase = w * 16 + i * 4;                                        \
      const int row = rbase + krow_off;                                        \
      const int cs = kchunk ^ (row & 15);                                      \
      load_lds16(Kb + (size_t)(kv0s + row) * Edim + cs * 8,                    \
                 &Ks[bufi][rbase * 128]);                                      \
    }                                                                          \
    _Pragma("unroll")                                                          \
    for (int i = 0; i < 4; ++i) {                                              \
      const int rbase = w * 32 + i * 8;                                        \
      const int row = rbase + vrow_off;                                        \
      const int cs = vchunk ^ (row & 7);                                       \
      load_lds16(Vb + (size_t)row * Sdim + kv0s + cs * 8,                      \
                 &Vs[bufi][rbase * 64]);                                       \
    }                                                                          \
  }

  STAGE(0, 0);
  __syncthreads();

  for (int t = 0; t < nt; ++t) {
    const int cur = t & 1;
    if (t + 1 < nt) STAGE(cur ^ 1, t + 1);

    if (t < ntw) {
      const int kv0 = t * 64;

      // ---- QK^T (swapped): 16 MFMAs, K frags from swizzled LDS ----
      f32x16 sc0, sc1;
#pragma unroll
      for (int i = 0; i < 16; ++i) { sc0[i] = 0.f; sc1[i] = 0.f; }
#pragma unroll
      for (int c = 0; c < 8; ++c) {
        const int ch = c * 2 + hi;
        const int r0r = l31;
        const int r1r = 32 + l31;
        bf16x8 kf0 = *(const bf16x8*)&Ks[cur][r0r * 128 + (ch ^ (r0r & 15)) * 8];
        bf16x8 kf1 = *(const bf16x8*)&Ks[cur][r1r * 128 + (ch ^ (r1r & 15)) * 8];
        sc0 = mfma32(kf0, qf[c], sc0);
        sc1 = mfma32(kf1, qf[c], sc1);
      }

      // ---- causal mask + row max (scores already in log2 units) ----
      float psc[32];
      float ma = -1e30f, mb = -1e30f, mc = -1e30f, md = -1e30f;
      if (kv0 + 64 > qw0) {  // diagonal tile: apply mask
#pragma unroll
        for (int r = 0; r < 16; ++r) {
          const int cr = (r & 3) + 8 * (r >> 2) + 4 * hi;
          float v0 = (kv0 + cr <= qrel) ? sc0[r] : -1e30f;
          float v1 = (kv0 + 32 + cr <= qrel) ? sc1[r] : -1e30f;
          psc[r] = v0; psc[16 + r] = v1;
          if ((r & 3) == 0) { ma = fmaxf(fmaxf(ma, v0), v1); }
          else if ((r & 3) == 1) { mb = fmaxf(fmaxf(mb, v0), v1); }
          else if ((r & 3) == 2) { mc = fmaxf(fmaxf(mc, v0), v1); }
          else { md = fmaxf(fmaxf(md, v0), v1); }
        }
      } else {
#pragma unroll
        for (int r = 0; r < 16; ++r) {
          float v0 = sc0[r];
          float v1 = sc1[r];
          psc[r] = v0; psc[16 + r] = v1;
          if ((r & 3) == 0) { ma = fmaxf(fmaxf(ma, v0), v1); }
          else if ((r & 3) == 1) { mb = fmaxf(fmaxf(mb, v0), v1); }
          else if ((r & 3) == 2) { mc = fmaxf(fmaxf(mc, v0), v1); }
          else { md = fmaxf(fmaxf(md, v0), v1); }
        }
      }
      float mt = fmaxf(fmaxf(ma, mb), fmaxf(mc, md));
      u32x2 mx = __builtin_amdgcn_permlane32_swap(
          __float_as_uint(mt), __float_as_uint(mt), false, false);
      float mo = fmaxf(__uint_as_float(mx.x), __uint_as_float(mx.y));

      // ---- defer-max rescale (T13, THR=8 in log2 units) ----
      if (__any(mo - m2 > 8.0f)) {
        float mnew = fmaxf(m2, mo);
        float corr = __builtin_amdgcn_exp2f(m2 - mnew);
        m2 = mnew;
        lacc[0] *= corr;
#pragma unroll
        for (int d = 0; d < 4; ++d)
#pragma unroll
          for (int i = 0; i < 16; ++i) oacc[d][i] *= corr;
      }

      // ---- exp ----
#pragma unroll
      for (int r = 0; r < 32; ++r)
        psc[r] = __builtin_amdgcn_exp2f(psc[r] - m2);

      // ---- P -> bf16 fragments (pack + permlane32_swap redistribution) ----
      u32 pk[16];
#pragma unroll
      for (int i = 0; i < 16; ++i) pk[i] = pkbf(psc[2 * i], psc[2 * i + 1]);
      bf16x8 pa[4];
#pragma unroll
      for (int t2 = 0; t2 < 2; ++t2)
#pragma unroll
        for (int q2 = 0; q2 < 2; ++q2) {
          const int base = t2 * 8 + q2 * 4;
          u32x2 r0 = __builtin_amdgcn_permlane32_swap(pk[base + 0], pk[base + 2],
                                                      false, false);
          u32x2 r1 = __builtin_amdgcn_permlane32_swap(pk[base + 1], pk[base + 3],
                                                      false, false);
          union { u32 wv[4]; bf16x8 v; } cv;
          cv.wv[0] = r0.x; cv.wv[1] = r1.x; cv.wv[2] = r0.y; cv.wv[3] = r1.y;
          pa[t2 * 2 + q2] = cv.v;
        }

      // ---- PV (swapped): 16 MFMAs + 4 ones-MFMAs (row sums) ----
#pragma unroll
      for (int dblk = 0; dblk < 4; ++dblk) {
        const int row = dblk * 32 + l31;
#pragma unroll
        for (int ks = 0; ks < 4; ++ks) {
          const int ch = ks * 2 + hi;
          bf16x8 vf = *(const bf16x8*)&Vs[cur][row * 64 + (ch ^ (row & 7)) * 8];
          oacc[dblk] = mfma32(vf, pa[ks], oacc[dblk]);
        }
      }
#pragma unroll
      for (int ks = 0; ks < 4; ++ks) lacc = mfma32(ones, pa[ks], lacc);
    }

    __syncthreads();
  }
#undef STAGE

  // ---- epilogue: divide by row sum, store f32x4 runs ----
  float inv = 1.0f / lacc[0];
  float* Ob = O + ((size_t)bh * Sdim + qw0 + l31) * Ddim + hi * 4;
#pragma unroll
  for (int dblk = 0; dblk < 4; ++dblk)
#pragma unroll
    for (int g = 0; g < 4; ++g) {
      f32x4 o4 = { oacc[dblk][4 * g] * inv, oacc[dblk][4 * g + 1] * inv,
                   oacc[dblk][4 * g + 2] * inv, oacc[dblk][4 * g + 3] * inv };
      *(f32x4*)(Ob + dblk * 32 + g * 8) = o4;
    }
}

extern "C" void kernel_launch(void* const* d_in, const int* in_sizes, int n_in,
                              void* d_out, int out_size, void* d_ws, size_t ws_size,
                              hipStream_t stream) {
  const float* x  = (const float*)d_in[0];
  const float* Wq = (const float*)d_in[1];
  const float* Wk = (const float*)d_in[2];
  const float* Wv = (const float*)d_in[3];
  float* out = (float*)d_out;
  char* ws = (char*)d_ws;

  // workspace layout (bytes)
  u16* xb  = (u16*)(ws);                    // 32 MiB  [B*S][E]
  u16* wqb = (u16*)(ws + 33554432ull);      //  8 MiB  [E][E]  (contiguous w/ wkb, wvb)
  u16* wkb = (u16*)(ws + 41943040ull);
  u16* wvb = (u16*)(ws + 50331648ull);
  u16* Qb  = (u16*)(ws + 58720256ull);      // 32 MiB
  u16* Kb  = (u16*)(ws + 92274688ull);      // 32 MiB
  u16* Vt  = (u16*)(ws + 125829120ull);     // 32 MiB  [B*H][128][S]

  const int nX = Bdim * Sdim * Edim;   // 16777216
  const int nW = Edim * Edim;          // 4194304
  const float K1SC = 0.08838834764831845f * 1.4426950408889634f;  // log2e/sqrt(D)
  cvt_kernel<<<(nX / 4 + 255) / 256, 256, 0, stream>>>(x, xb, nX / 4, 1.0f);
  cvt_w_kernel<<<(3 * nW / 4 + 255) / 256, 256, 0, stream>>>(Wq, Wk, Wv, wqb, K1SC);

  dim3 g(Bdim * Sdim / 256, Edim / 256);  // (32, 8)
  gemm_nt<false><<<g, 512, 0, stream>>>(xb, wqb, Qb, Bdim * Sdim, Edim, Edim);
  gemm_nt<false><<<g, 512, 0, stream>>>(xb, wkb, Kb, Bdim * Sdim, Edim, Edim);
  gemm_nt<true ><<<g, 512, 0, stream>>>(xb, wvb, Vt, Bdim * Sdim, Edim, Edim);

  attn_kernel<<<Bdim * Hdim * (Sdim / 128), 256, 0, stream>>>(Qb, Kb, Vt, out);
}

// Round 17
// 361.999 us; speedup vs baseline: 1.0099x; 1.0099x over previous
//
#include <hip/hip_runtime.h>
#include <hip/hip_bf16.h>
#include <stdint.h>

#define Bdim 4
#define Sdim 2048
#define Edim 2048
#define Hdim 16
#define Ddim 128

typedef unsigned short u16;
typedef unsigned int u32;
typedef __attribute__((ext_vector_type(8))) short bf16x8;
typedef __attribute__((ext_vector_type(4))) float f32x4;
typedef __attribute__((ext_vector_type(16))) float f32x16;
typedef __attribute__((ext_vector_type(4))) unsigned short u16x4;
typedef __attribute__((ext_vector_type(2))) unsigned int u32x2;

__device__ inline u16 f2bf(float f) {
  union { float f; uint32_t u; } v; v.f = f;
  uint32_t u = v.u;
  return (u16)((u + 0x7FFFu + ((u >> 16) & 1u)) >> 16);
}

__device__ inline u32 pkbf(float lo, float hi) {
  float2 t; t.x = lo; t.y = hi;
  union { __hip_bfloat162 h2; u32 u; } cv;
  cv.h2 = __float22bfloat162_rn(t);
  return cv.u;
}

__device__ inline f32x4 mfma16(bf16x8 a, bf16x8 b, f32x4 c) {
  return __builtin_amdgcn_mfma_f32_16x16x32_bf16(a, b, c, 0, 0, 0);
}
__device__ inline f32x16 mfma32(bf16x8 a, bf16x8 b, f32x16 c) {
  return __builtin_amdgcn_mfma_f32_32x32x16_bf16(a, b, c, 0, 0, 0);
}

// async global->LDS, 16B per lane; lds dest = wave-uniform base + lane*16
__device__ inline void load_lds16(const void* g, const void* l) {
  __builtin_amdgcn_global_load_lds(
      (__attribute__((address_space(1))) void*)(uintptr_t)g,
      (__attribute__((address_space(3))) void*)(uint32_t)(uintptr_t)l,
      16, 0, 0);
}

__global__ void cvt_kernel(const float* __restrict__ src, u16* __restrict__ dst,
                           int n4, float scale) {
  int i = blockIdx.x * blockDim.x + threadIdx.x;
  if (i < n4) {
    float4 f = ((const float4*)src)[i];
    u16x4 o = { f2bf(f.x * scale), f2bf(f.y * scale),
                f2bf(f.z * scale), f2bf(f.w * scale) };
    ((u16x4*)dst)[i] = o;
  }
}

// fused Wq/Wk/Wv cvt; dst = contiguous wqb|wkb|wvb region; Wq pre-scaled
__global__ void cvt_w_kernel(const float* __restrict__ Wq,
                             const float* __restrict__ Wk,
                             const float* __restrict__ Wv,
                             u16* __restrict__ dst, float qscale) {
  int i = blockIdx.x * blockDim.x + threadIdx.x;  // over 3 * (E*E/4)
  int seg = i >> 20;                              // E*E/4 = 1048576
  int off = i & 1048575;
  const float* src = seg == 0 ? Wq : (seg == 1 ? Wk : Wv);
  float sc = seg == 0 ? qscale : 1.0f;
  float4 f = ((const float4*)src)[off];
  u16x4 o = { f2bf(f.x * sc), f2bf(f.y * sc), f2bf(f.z * sc), f2bf(f.w * sc) };
  ((u16x4*)dst)[i] = o;
}

// C[m][n] = sum_k A[m][k] * Bw[n][k]   (A:[M][K], Bw:[N][K], bf16 in/out)
// m201-style 4-phase/BK=64 schedule (round-13, best measured): 256x256 tile,
// 8 waves (2M x 4N), LDS = 2 dbuf x 4 half-tiles (Ah0|Ah1|Bh0|Bh1, 16KB each)
// = 128KB. Per K-tile, 4 phases: {stage 1 half of t+1; ds_read one half's
// frags; 16 MFMA; counted vmcnt(4/4/6/4); s_barrier} -- stages live across
// barriers (never vmcnt(0) mid-loop). Stage order [Ah0,Bh0,Bh1,Ah1] gives
// each half >=3 phases of load-latency cover. Fragment maps: row(m)=
// (m&3)*32+wm*16+(m>>2)*128, col(n)=(n&1)*64+wn*16+(n>>1)*128 so each phase
// reads one half. Swizzle: read chunk=(kk*4+l4)^(l15&7), stage src chunk=
// (lane&7)^(lane>>3). TRANSV: store into Vt[(b*H+h)][d][s].
template <bool TRANSV>
__global__ __launch_bounds__(512, 2)
void gemm_nt(const u16* __restrict__ A, const u16* __restrict__ Bw,
             u16* __restrict__ C, int M, int N, int K) {
  __shared__ char lds[131072];  // [2 buf][Ah0|Ah1|Bh0|Bh1]

  const int tid = threadIdx.x;
  const int lane = tid & 63;
  const int w = tid >> 6;            // 0..7
  const int wm = w >> 2, wn = w & 3; // 2 x 4 wave grid
  const int bm = blockIdx.x, bn = blockIdx.y;
  const int NT = K >> 6;             // K-tiles of 64

  const int l15 = lane & 15;
  const int l4 = lane >> 4;          // k-subchunk 0..3
  const int h7 = l15 & 7;

  // stage lane constants: per half-tile 2 issues; issue i covers rows
  // w*8+srow + i*64 (8 rows x 128B per wave per issue)
  const int srow = lane >> 3;               // 0..7
  const int schunk = (lane & 7) ^ srow;     // pre-swizzled source chunk

  // fragment byte offsets within a half (lrow*128 + chunk*16)
  const int ck0 = (l4 ^ h7) << 4;           // kk=0
  const int ck1 = ((4 + l4) ^ h7) << 4;     // kk=1
  const int arow0 = (wm * 16 + l15) * 128;  // A q-base; q adds 4096
  const int brow0 = (wn * 16 + l15) * 128;  // B n-base; (n&1) adds 8192

  const u16* Agp = A + (size_t)(bm * 256) * K;
  const u16* Bgp = Bw + (size_t)(bn * 256) * K;

  f32x4 acc[8][4];
#pragma unroll
  for (int m = 0; m < 8; ++m)
#pragma unroll
    for (int n = 0; n < 4; ++n)
      acc[m][n] = (f32x4){0.f, 0.f, 0.f, 0.f};

#define STG_A(hh, tt)                                                          \
  {                                                                            \
    char* d_ = lds + ((tt) & 1) * 65536 + (hh) * 16384;                        \
    _Pragma("unroll")                                                          \
    for (int i_ = 0; i_ < 2; ++i_)                                             \
      load_lds16(Agp + (size_t)((hh) * 128 + w * 8 + srow + i_ * 64) * K +     \
                     (tt) * 64 + schunk * 8,                                   \
                 d_ + (w * 8 + i_ * 64) * 128);                                \
  }
#define STG_B(hh, tt)                                                          \
  {                                                                            \
    char* d_ = lds + ((tt) & 1) * 65536 + 32768 + (hh) * 16384;                \
    _Pragma("unroll")                                                          \
    for (int i_ = 0; i_ < 2; ++i_)                                             \
      load_lds16(Bgp + (size_t)((hh) * 128 + w * 8 + srow + i_ * 64) * K +     \
                     (tt) * 64 + schunk * 8,                                   \
                 d_ + (w * 8 + i_ * 64) * 128);                                \
  }

  // prologue: all 4 halves of tile 0, in steady-state order
  STG_A(0, 0); STG_B(0, 0); STG_B(1, 0); STG_A(1, 0);
  asm volatile("s_waitcnt vmcnt(0)" ::: "memory");
  __builtin_amdgcn_s_barrier();

  for (int t = 0; t < NT; ++t) {
    const char* bc = lds + (t & 1) * 65536;
    const bool pf = (t + 1 < NT);

    // ---- phase 0: stage Ah0(t+1) | read Am0-3 + Bn0-1 | MFMA m0-3 x n0-1 ----
    if (pf) STG_A(0, t + 1);
    bf16x8 a0[4][2], b0[2][2];
#pragma unroll
    for (int q = 0; q < 4; ++q) {
      a0[q][0] = *(const bf16x8*)(bc + arow0 + q * 4096 + ck0);
      a0[q][1] = *(const bf16x8*)(bc + arow0 + q * 4096 + ck1);
    }
#pragma unroll
    for (int n = 0; n < 2; ++n) {
      b0[n][0] = *(const bf16x8*)(bc + 32768 + brow0 + n * 8192 + ck0);
      b0[n][1] = *(const bf16x8*)(bc + 32768 + brow0 + n * 8192 + ck1);
    }
    __builtin_amdgcn_s_setprio(1);
#pragma unroll
    for (int q = 0; q < 4; ++q)
#pragma unroll
      for (int n = 0; n < 2; ++n) {
        acc[q][n] = mfma16(a0[q][0], b0[n][0], acc[q][n]);
        acc[q][n] = mfma16(a0[q][1], b0[n][1], acc[q][n]);
      }
    __builtin_amdgcn_s_setprio(0);
    asm volatile("s_waitcnt vmcnt(4)" ::: "memory");
    __builtin_amdgcn_s_barrier();

    // ---- phase 1: stage Bh0(t+1) | read Bn2-3 | MFMA m0-3 x n2-3 ----
    if (pf) STG_B(0, t + 1);
    bf16x8 b1[2][2];
#pragma unroll
    for (int n = 0; n < 2; ++n) {
      b1[n][0] = *(const bf16x8*)(bc + 49152 + brow0 + n * 8192 + ck0);
      b1[n][1] = *(const bf16x8*)(bc + 49152 + brow0 + n * 8192 + ck1);
    }
    __builtin_amdgcn_s_setprio(1);
#pragma unroll
    for (int q = 0; q < 4; ++q)
#pragma unroll
      for (int n = 0; n < 2; ++n) {
        acc[q][n + 2] = mfma16(a0[q][0], b1[n][0], acc[q][n + 2]);
        acc[q][n + 2] = mfma16(a0[q][1], b1[n][1], acc[q][n + 2]);
      }
    __builtin_amdgcn_s_setprio(0);
    asm volatile("s_waitcnt vmcnt(4)" ::: "memory");
    __builtin_amdgcn_s_barrier();

    // ---- phase 2: stage Bh1(t+1) | read Am4-7 | MFMA m4-7 x n2-3 ----
    if (pf) STG_B(1, t + 1);
    bf16x8 a1[4][2];
#pragma unroll
    for (int q = 0; q < 4; ++q) {
      a1[q][0] = *(const bf16x8*)(bc + 16384 + arow0 + q * 4096 + ck0);
      a1[q][1] = *(const bf16x8*)(bc + 16384 + arow0 + q * 4096 + ck1);
    }
    __builtin_amdgcn_s_setprio(1);
#pragma unroll
    for (int q = 0; q < 4; ++q)
#pragma unroll
      for (int n = 0; n < 2; ++n) {
        acc[q + 4][n + 2] = mfma16(a1[q][0], b1[n][0], acc[q + 4][n + 2]);
        acc[q + 4][n + 2] = mfma16(a1[q][1], b1[n][1], acc[q + 4][n + 2]);
      }
    __builtin_amdgcn_s_setprio(0);
    asm volatile("s_waitcnt vmcnt(6)" ::: "memory");
    __builtin_amdgcn_s_barrier();

    // ---- phase 3: stage Ah1(t+1) | (no reads) | MFMA m4-7 x n0-1 ----
    if (pf) STG_A(1, t + 1);
    __builtin_amdgcn_s_setprio(1);
#pragma unroll
    for (int q = 0; q < 4; ++q)
#pragma unroll
      for (int n = 0; n < 2; ++n) {
        acc[q + 4][n] = mfma16(a1[q][0], b0[n][0], acc[q + 4][n]);
        acc[q + 4][n] = mfma16(a1[q][1], b0[n][1], acc[q + 4][n]);
      }
    __builtin_amdgcn_s_setprio(0);
    asm volatile("s_waitcnt vmcnt(4)" ::: "memory");
    __builtin_amdgcn_s_barrier();
  }
#undef STG_A
#undef STG_B

  // epilogue: row(m) = (m&3)*32 + wm*16 + (m>>2)*128; col(n) = (n&1)*64 +
  // wn*16 + (n>>1)*128; within-frag: row += l4*4 + j, col += l15.
#pragma unroll
  for (int m = 0; m < 8; ++m)
#pragma unroll
    for (int n = 0; n < 4; ++n) {
      int r = bm * 256 + (m & 3) * 32 + wm * 16 + (m >> 2) * 128 + (l4 << 2);
      int c = bn * 256 + (n & 1) * 64 + wn * 16 + (n >> 1) * 128 + l15;
      if (!TRANSV) {
#pragma unroll
        for (int j = 0; j < 4; ++j)
          C[(size_t)(r + j) * N + c] = f2bf(acc[m][n][j]);
      } else {
        int h = c >> 7, d = c & 127;
        int b = r >> 11, s = r & 2047;
        u16x4 pk = { f2bf(acc[m][n][0]), f2bf(acc[m][n][1]),
                     f2bf(acc[m][n][2]), f2bf(acc[m][n][3]) };
        *(u16x4*)(C + ((size_t)((b * Hdim + h) * Ddim + d)) * Sdim + s) = pk;
      }
    }
}

// Causal flash attention, swapped-operand 32x32 MFMA (round-5 verbatim —
// measured best 154us; frozen). Block = 4 waves sharing one head and a
// 128-row q-block; each wave owns 32 q rows. KV tile = 64, double-buffered in
// LDS (K swizzled ^row&15, V ^row&7), staged via global_load_lds with
// pre-swizzled global source; 2-phase pipeline. Q PRE-SCALED by
// log2e/sqrt(D); row sums via ones-MFMA into lacc; P redistribution via
// v_permlane32_swap; defer-max rescale (THR=8).
__global__ __launch_bounds__(256)
void attn_kernel(const u16* __restrict__ Q, const u16* __restrict__ K,
                 const u16* __restrict__ Vt, float* __restrict__ O) {
  __shared__ u16 Ks[2][64 * 128];
  __shared__ u16 Vs[2][128 * 64];

  const int tid = threadIdx.x;
  const int lane = tid & 63;
  const int w = tid >> 6;
  const int l31 = lane & 31;
  const int hi = lane >> 5;

  const int bid = blockIdx.x;
  const int bh = bid & 63;              // head index b*16+h
  const int qg = 15 - (bid >> 6);       // longest q-groups dispatch first
  const int q0 = qg * 128;
  const int qw0 = q0 + w * 32;          // this wave's 32 q rows
  const int b = bh >> 4, h = bh & 15;

  const u16* Qb = Q + (size_t)b * Sdim * Edim + h * Ddim;
  const u16* Kb = K + (size_t)b * Sdim * Edim + h * Ddim;
  const u16* Vb = Vt + (size_t)bh * Ddim * Sdim;

  // Q fragments (B-operand): lane: q row = qw0+l31, k = c*16 + hi*8 + e
  bf16x8 qf[8];
  {
    const u16* qrow = Qb + (size_t)(qw0 + l31) * Edim + hi * 8;
#pragma unroll
    for (int c = 0; c < 8; ++c) qf[c] = *(const bf16x8*)(qrow + c * 16);
  }

  f32x16 oacc[4];
#pragma unroll
  for (int d = 0; d < 4; ++d)
#pragma unroll
    for (int i = 0; i < 16; ++i) oacc[d][i] = 0.f;
  f32x16 lacc;
#pragma unroll
  for (int i = 0; i < 16; ++i) lacc[i] = 0.f;

  const short oneb = (short)0x3F80;
  const bf16x8 ones = {oneb, oneb, oneb, oneb, oneb, oneb, oneb, oneb};

  float m2 = -1e30f;
  const int qrel = qw0 + l31;

  const int nt = 2 * qg + 2;                 // block's causal tile count
  const int ntw = (qw0 + 31) / 64 + 1;       // this wave's tile count

  // staging lane constants
  const int krow_off = (lane >> 4);          // K: 4 rows per 1KB issue
  const int kchunk = lane & 15;
  const int vrow_off = (lane >> 3);          // V: 8 rows per 1KB issue
  const int vchunk = lane & 7;

#define STAGE(bufi, tt)                                                        \
  {                                                                            \
    const int kv0s = (tt) * 64;                                                \
    _Pragma("unroll")                                                          \
    for (int i = 0; i < 4; ++i) {                                              \
      const int rbase = w * 16 + i * 4;                                        \
      const int row = rbase + krow_off;                                        \
      const int cs = kchunk ^ (row & 15);                                      \
      load_lds16(Kb + (size_t)(kv0s + row) * Edim + cs * 8,                    \
                 &Ks[bufi][rbase * 128]);                                      \
    }                                                                          \
    _Pragma("unroll")                                                          \
    for (int i = 0; i < 4; ++i) {                                              \
      const int rbase = w * 32 + i * 8;                                        \
      const int row = rbase + vrow_off;                                        \
      const int cs = vchunk ^ (row & 7);                                       \
      load_lds16(Vb + (size_t)row * Sdim + kv0s + cs * 8,                      \
                 &Vs[bufi][rbase * 64]);                                       \
    }                                                                          \
  }

  STAGE(0, 0);
  __syncthreads();

  for (int t = 0; t < nt; ++t) {
    const int cur = t & 1;
    if (t + 1 < nt) STAGE(cur ^ 1, t + 1);

    if (t < ntw) {
      const int kv0 = t * 64;

      // ---- QK^T (swapped): 16 MFMAs, K frags from swizzled LDS ----
      f32x16 sc0, sc1;
#pragma unroll
      for (int i = 0; i < 16; ++i) { sc0[i] = 0.f; sc1[i] = 0.f; }
#pragma unroll
      for (int c = 0; c < 8; ++c) {
        const int ch = c * 2 + hi;
        const int r0r = l31;
        const int r1r = 32 + l31;
        bf16x8 kf0 = *(const bf16x8*)&Ks[cur][r0r * 128 + (ch ^ (r0r & 15)) * 8];
        bf16x8 kf1 = *(const bf16x8*)&Ks[cur][r1r * 128 + (ch ^ (r1r & 15)) * 8];
        sc0 = mfma32(kf0, qf[c], sc0);
        sc1 = mfma32(kf1, qf[c], sc1);
      }

      // ---- causal mask + row max (scores already in log2 units) ----
      float psc[32];
      float ma = -1e30f, mb = -1e30f, mc = -1e30f, md = -1e30f;
      if (kv0 + 64 > qw0) {  // diagonal tile: apply mask
#pragma unroll
        for (int r = 0; r < 16; ++r) {
          const int cr = (r & 3) + 8 * (r >> 2) + 4 * hi;
          float v0 = (kv0 + cr <= qrel) ? sc0[r] : -1e30f;
          float v1 = (kv0 + 32 + cr <= qrel) ? sc1[r] : -1e30f;
          psc[r] = v0; psc[16 + r] = v1;
          if ((r & 3) == 0) { ma = fmaxf(fmaxf(ma, v0), v1); }
          else if ((r & 3) == 1) { mb = fmaxf(fmaxf(mb, v0), v1); }
          else if ((r & 3) == 2) { mc = fmaxf(fmaxf(mc, v0), v1); }
          else { md = fmaxf(fmaxf(md, v0), v1); }
        }
      } else {
#pragma unroll
        for (int r = 0; r < 16; ++r) {
          float v0 = sc0[r];
          float v1 = sc1[r];
          psc[r] = v0; psc[16 + r] = v1;
          if ((r & 3) == 0) { ma = fmaxf(fmaxf(ma, v0), v1); }
          else if ((r & 3) == 1) { mb = fmaxf(fmaxf(mb, v0), v1); }
          else if ((r & 3) == 2) { mc = fmaxf(fmaxf(mc, v0), v1); }
          else { md = fmaxf(fmaxf(md, v0), v1); }
        }
      }
      float mt = fmaxf(fmaxf(ma, mb), fmaxf(mc, md));
      u32x2 mx = __builtin_amdgcn_permlane32_swap(
          __float_as_uint(mt), __float_as_uint(mt), false, false);
      float mo = fmaxf(__uint_as_float(mx.x), __uint_as_float(mx.y));

      // ---- defer-max rescale (T13, THR=8 in log2 units) ----
      if (__any(mo - m2 > 8.0f)) {
        float mnew = fmaxf(m2, mo);
        float corr = __builtin_amdgcn_exp2f(m2 - mnew);
        m2 = mnew;
        lacc[0] *= corr;
#pragma unroll
        for (int d = 0; d < 4; ++d)
#pragma unroll
          for (int i = 0; i < 16; ++i) oacc[d][i] *= corr;
      }

      // ---- exp ----
#pragma unroll
      for (int r = 0; r < 32; ++r)
        psc[r] = __builtin_amdgcn_exp2f(psc[r] - m2);

      // ---- P -> bf16 fragments (pack + permlane32_swap redistribution) ----
      u32 pk[16];
#pragma unroll
      for (int i = 0; i < 16; ++i) pk[i] = pkbf(psc[2 * i], psc[2 * i + 1]);
      bf16x8 pa[4];
#pragma unroll
      for (int t2 = 0; t2 < 2; ++t2)
#pragma unroll
        for (int q2 = 0; q2 < 2; ++q2) {
          const int base = t2 * 8 + q2 * 4;
          u32x2 r0 = __builtin_amdgcn_permlane32_swap(pk[base + 0], pk[base + 2],
                                                      false, false);
          u32x2 r1 = __builtin_amdgcn_permlane32_swap(pk[base + 1], pk[base + 3],
                                                      false, false);
          union { u32 wv[4]; bf16x8 v; } cv;
          cv.wv[0] = r0.x; cv.wv[1] = r1.x; cv.wv[2] = r0.y; cv.wv[3] = r1.y;
          pa[t2 * 2 + q2] = cv.v;
        }

      // ---- PV (swapped): 16 MFMAs + 4 ones-MFMAs (row sums) ----
#pragma unroll
      for (int dblk = 0; dblk < 4; ++dblk) {
        const int row = dblk * 32 + l31;
#pragma unroll
        for (int ks = 0; ks < 4; ++ks) {
          const int ch = ks * 2 + hi;
          bf16x8 vf = *(const bf16x8*)&Vs[cur][row * 64 + (ch ^ (row & 7)) * 8];
          oacc[dblk] = mfma32(vf, pa[ks], oacc[dblk]);
        }
      }
#pragma unroll
      for (int ks = 0; ks < 4; ++ks) lacc = mfma32(ones, pa[ks], lacc);
    }

    __syncthreads();
  }
#undef STAGE

  // ---- epilogue: divide by row sum, store f32x4 runs ----
  float inv = 1.0f / lacc[0];
  float* Ob = O + ((size_t)bh * Sdim + qw0 + l31) * Ddim + hi * 4;
#pragma unroll
  for (int dblk = 0; dblk < 4; ++dblk)
#pragma unroll
    for (int g = 0; g < 4; ++g) {
      f32x4 o4 = { oacc[dblk][4 * g] * inv, oacc[dblk][4 * g + 1] * inv,
                   oacc[dblk][4 * g + 2] * inv, oacc[dblk][4 * g + 3] * inv };
      *(f32x4*)(Ob + dblk * 32 + g * 8) = o4;
    }
}

extern "C" void kernel_launch(void* const* d_in, const int* in_sizes, int n_in,
                              void* d_out, int out_size, void* d_ws, size_t ws_size,
                              hipStream_t stream) {
  const float* x  = (const float*)d_in[0];
  const float* Wq = (const float*)d_in[1];
  const float* Wk = (const float*)d_in[2];
  const float* Wv = (const float*)d_in[3];
  float* out = (float*)d_out;
  char* ws = (char*)d_ws;

  // workspace layout (bytes)
  u16* xb  = (u16*)(ws);                    // 32 MiB  [B*S][E]
  u16* wqb = (u16*)(ws + 33554432ull);      //  8 MiB  [E][E]  (contiguous w/ wkb, wvb)
  u16* wkb = (u16*)(ws + 41943040ull);
  u16* wvb = (u16*)(ws + 50331648ull);
  u16* Qb  = (u16*)(ws + 58720256ull);      // 32 MiB
  u16* Kb  = (u16*)(ws + 92274688ull);      // 32 MiB
  u16* Vt  = (u16*)(ws + 125829120ull);     // 32 MiB  [B*H][128][S]

  const int nX = Bdim * Sdim * Edim;   // 16777216
  const int nW = Edim * Edim;          // 4194304
  const float K1SC = 0.08838834764831845f * 1.4426950408889634f;  // log2e/sqrt(D)
  cvt_kernel<<<(nX / 4 + 255) / 256, 256, 0, stream>>>(x, xb, nX / 4, 1.0f);
  cvt_w_kernel<<<(3 * nW / 4 + 255) / 256, 256, 0, stream>>>(Wq, Wk, Wv, wqb, K1SC);

  dim3 g(Bdim * Sdim / 256, Edim / 256);  // (32, 8)
  gemm_nt<false><<<g, 512, 0, stream>>>(xb, wqb, Qb, Bdim * Sdim, Edim, Edim);
  gemm_nt<false><<<g, 512, 0, stream>>>(xb, wkb, Kb, Bdim * Sdim, Edim, Edim);
  gemm_nt<true ><<<g, 512, 0, stream>>>(xb, wvb, Vt, Bdim * Sdim, Edim, Edim);

  attn_kernel<<<Bdim * Hdim * (Sdim / 128), 256, 0, stream>>>(Qb, Kb, Vt, out);
}